// Round 10
// baseline (149.159 us; speedup 1.0000x reference)
//
#include <hip/hip_runtime.h>

#define EPS 1e-5f

typedef float f2 __attribute__((ext_vector_type(2)));
typedef float f4 __attribute__((ext_vector_type(4)));

// Broadcast a block-uniform load into an SGPR (scalars).
__device__ __forceinline__ float uload(const float* __restrict__ p) {
  return __int_as_float(__builtin_amdgcn_readfirstlane(__float_as_int(*p)));
}

__device__ __forceinline__ f2 fma2(f2 a, f2 b, f2 c) {
  return __builtin_elementwise_fma(a, b, c);
}
__device__ __forceinline__ f2 splat2(float s) { f2 r; r.x = s; r.y = s; return r; }

// ---------------------------------------------------------------------------
// K12: fused conv1(1->8)+ReLU+pool + conv2(4 used oc of 16)+ReLU+pool + sum,
//      PLUS the quantum/batchnorm/head tail run by the LAST block to finish.
// Block = (batch b, quarter q): pooled2 rows 8q..8q+7, 256 threads.
// Hard-won notes (r1-r9):
//  - conv1 reads x from GLOBAL. LDS xtile stride-2 reads = 1.06M conflict
//    cycles (r4). Never again.
//  - launch_bounds (256,6) -> scratch spill, 95 MB HBM writes (r5). Keep
//    (256,4); occupancy >4 blocks/CU buys nothing (r6).
//  - pk_fma halved VALU-busy to ~22 us (r7, matched prediction).
//  - r9 software-pipelining (batched xin arrays) -> 5.6 MB scratch spill,
//    neutral. HIP-level pipelining keeps losing; reverted to r8 body.
//  - r8 profile: harness d_ws fill (268 MB = ~44 us) dominates; only the
//    k3 dispatch gap is still controllable -> fused here as last-block tail
//    (device-scope atomic + threadfence, counter memset-async per call).
// ---------------------------------------------------------------------------
__global__ __launch_bounds__(256, 4) void k12_fused(
    const float* __restrict__ x, const float* __restrict__ w1,
    const float* __restrict__ b1, const float* __restrict__ w2,
    const float* __restrict__ b2, float* __restrict__ partials,
    unsigned int* __restrict__ counter, const float* __restrict__ qp,
    const float* __restrict__ gamma, const float* __restrict__ beta,
    const float* __restrict__ hw, const float* __restrict__ hb,
    float* __restrict__ out) {
  __shared__ float p1[8][18][66];  // pooled1 tile; col idx = col+1 (halo)
  __shared__ float w1t[80];        // [k][oc8] transposed (72) + b1[8] at 72..
  __shared__ float w2t[292];       // [ic8][k9][oc4] transposed + b2[4] at 288..
  __shared__ float wred[4][4];
  __shared__ float tsum[4][8];     // tail: per-wave sums
  __shared__ float tstats[8];      // tail: mu[4], E[q^2][4]
  __shared__ bool  is_last;

  const int q   = blockIdx.x & 3;
  const int b   = blockIdx.x >> 2;
  const int tid = threadIdx.x;
  const float* xb = x + (size_t)b * (128 * 128);

  // ---- stage weights transposed ----
  if (tid < 72) {
    int oc = tid / 9, k = tid % 9;
    w1t[k * 8 + oc] = w1[tid];
  } else if (tid < 80) {
    w1t[tid] = b1[tid - 72];
  }
  {
    int t = tid;  // first 288 floats of w2 = oc 0..3
    {
      int oc = t / 72, rem = t % 72, ic = rem / 9, k = rem % 9;
      w2t[(ic * 9 + k) * 4 + oc] = w2[t];
    }
    t = tid + 256;
    if (t < 288) {
      int oc = t / 72, rem = t % 72, ic = rem / 9, k = rem % 9;
      w2t[(ic * 9 + k) * 4 + oc] = w2[t];
    }
  }
  if (tid >= 80 && tid < 84) w2t[288 + tid - 80] = b2[tid - 80];
  // zero p1's SAME-padding halo columns (8 channels x 18 rows)
  if (tid >= 96 && tid < 240) {
    int t = tid - 96;
    int ic = t / 18, r = t % 18;
    p1[ic][r][0]  = 0.f;
    p1[ic][r][65] = 0.f;
  }
  __syncthreads();

  // ---- conv1 + ReLU + pool, ALL 8 channels, x window loaded ONCE ----
  // 576 tasks = (gl 0..17, col-pair i 0..31); task loop, no HIP pipelining.
#pragma unroll 1
  for (int pos = tid; pos < 576; pos += 256) {
    const int gl = pos >> 5, i = pos & 31;
    const int G  = 16 * q - 1 + gl;
    const bool vG = ((unsigned)G) < 64u;
    const int xr0 = 2 * G - 1;
    float xin[4][6];  // x cols 4i-1 .. 4i+4, rows xr0..xr0+3 (masked)
#pragma unroll
    for (int r = 0; r < 4; ++r) {
      const int row  = xr0 + r;
      const bool rok = vG && ((unsigned)row < 128u);
      const int rowc = min(max(row, 0), 127);
      const float* rp = xb + rowc * 128;
      const float le = rp[(i == 0) ? 0 : (4 * i - 1)];
      const f4 mid   = *(const f4*)(rp + 4 * i);        // 16B-aligned
      const float ri = rp[(i == 31) ? 127 : (4 * i + 4)];
      xin[r][0] = (rok && i != 0)  ? le    : 0.f;
      xin[r][1] = rok              ? mid.x : 0.f;
      xin[r][2] = rok              ? mid.y : 0.f;
      xin[r][3] = rok              ? mid.z : 0.f;
      xin[r][4] = rok              ? mid.w : 0.f;
      xin[r][5] = (rok && i != 31) ? ri    : 0.f;
    }
    // Two sequential oc-halves so only 18+2 weight f2s are live at a time.
#pragma unroll 1
    for (int g = 0; g < 2; ++g) {
      f2 wpx[9][2], bias1[2];
#pragma unroll
      for (int k = 0; k < 9; ++k) {
        wpx[k][0] = *(const f2*)&w1t[k * 8 + 4 * g];
        wpx[k][1] = *(const f2*)&w1t[k * 8 + 4 * g + 2];
      }
      bias1[0] = *(const f2*)&w1t[72 + 4 * g];
      bias1[1] = *(const f2*)&w1t[72 + 4 * g + 2];
#pragma unroll
      for (int p = 0; p < 2; ++p)
#pragma unroll
        for (int h = 0; h < 2; ++h) {  // pooled col 2i+h
          f2 best = splat2(0.f);       // ReLU floor
#pragma unroll
          for (int dy = 0; dy < 2; ++dy)
#pragma unroll
            for (int dx = 0; dx < 2; ++dx) {
              f2 a = bias1[p];
#pragma unroll
              for (int ky = 0; ky < 3; ++ky)
#pragma unroll
                for (int kx = 0; kx < 3; ++kx)
                  a = fma2(wpx[ky * 3 + kx][p],
                           splat2(xin[dy + ky][2 * h + dx + kx]), a);
              best.x = fmaxf(best.x, a.x);
              best.y = fmaxf(best.y, a.y);
            }
          const int oc0 = 4 * g + 2 * p;
          p1[oc0][gl][2 * i + 1 + h]     = vG ? best.x : 0.f;
          p1[oc0 + 1][gl][2 * i + 1 + h] = vG ? best.y : 0.f;
        }
    }
  }
  __syncthreads();

  // ---- conv2 (oc 0..3 packed as 2 f2 pairs) + ReLU + pool + sum ----
  const int px2  = tid & 31;
  const int py2l = tid >> 5;  // 0..7

  f2 acc[2][2][2];  // [ocpair p][dy][dx]
#pragma unroll
  for (int p = 0; p < 2; ++p) {
    const f2 bias = *(const f2*)&w2t[288 + 2 * p];
    acc[p][0][0] = bias; acc[p][0][1] = bias;
    acc[p][1][0] = bias; acc[p][1][1] = bias;
  }

#pragma unroll 1
  for (int ic = 0; ic < 8; ++ic) {
    float xin[4][4];
#pragma unroll
    for (int r = 0; r < 4; ++r) {
      // even 8B-aligned float2 reads — near-0 conflicts (r3)
      const f2* rp = (const f2*)&p1[ic][2 * py2l + r][2 * px2];
      f2 v0 = rp[0], v1 = rp[1];
      xin[r][0] = v0.x; xin[r][1] = v0.y; xin[r][2] = v1.x; xin[r][3] = v1.y;
    }
#pragma unroll
    for (int ky = 0; ky < 3; ++ky)
#pragma unroll
      for (int kx = 0; kx < 3; ++kx) {
        const int k = ky * 3 + kx;
        const f2 w0  = *(const f2*)&w2t[(ic * 9 + k) * 4];
        const f2 w1p = *(const f2*)&w2t[(ic * 9 + k) * 4 + 2];
#pragma unroll
        for (int dy = 0; dy < 2; ++dy)
#pragma unroll
          for (int dx = 0; dx < 2; ++dx) {
            const f2 xs = splat2(xin[dy + ky][dx + kx]);
            acc[0][dy][dx] = fma2(w0, xs, acc[0][dy][dx]);
            acc[1][dy][dx] = fma2(w1p, xs, acc[1][dy][dx]);
          }
      }
  }

  // ---- ReLU + 2x2 pool + spatial partial-sum ----
  const int lane = tid & 63, w = tid >> 6;
#pragma unroll
  for (int p = 0; p < 2; ++p) {
    f2 m01;
    m01.x = fmaxf(fmaxf(fmaxf(acc[p][0][0].x, acc[p][0][1].x),
                        fmaxf(acc[p][1][0].x, acc[p][1][1].x)), 0.f);
    m01.y = fmaxf(fmaxf(fmaxf(acc[p][0][0].y, acc[p][0][1].y),
                        fmaxf(acc[p][1][0].y, acc[p][1][1].y)), 0.f);
#pragma unroll
    for (int off = 32; off > 0; off >>= 1) {
      m01.x += __shfl_down(m01.x, off);
      m01.y += __shfl_down(m01.y, off);
    }
    if (lane == 0) { wred[w][2 * p] = m01.x; wred[w][2 * p + 1] = m01.y; }
  }
  __syncthreads();
  if (tid < 4) {
    float s = wred[0][tid] + wred[1][tid] + wred[2][tid] + wred[3][tid];
    partials[((size_t)b * 4 + q) * 4 + tid] = s;
  }

  // ---- last-block-done gate (device-scope; cross-XCD per G16) ----
  if (tid == 0) {
    __threadfence();                       // release partials (wave 0 stores)
    unsigned int prev = atomicAdd(counter, 1u);
    is_last = (prev == 2047u);
  }
  __syncthreads();
  if (!is_last) return;
  __threadfence();                         // acquire: see all blocks' partials

  // =================== TAIL: quantum + batchnorm + head ===================
  // 256 threads, each handles batches {tid, tid+256}.
  float qv2[2][4];
  float v[8];
#pragma unroll
  for (int k = 0; k < 8; ++k) v[k] = 0.f;

#pragma unroll 1
  for (int half = 0; half < 2; ++half) {
    const int bt = tid + half * 256;
    const f4* pp = (const f4*)(partials + bt * 16);
    f4 s0 = pp[0], s1 = pp[1], s2 = pp[2], s3 = pp[3];
    float f[4];
    f[0] = (s0.x + s1.x + s2.x + s3.x) * (1.f / 1024.f);
    f[1] = (s0.y + s1.y + s2.y + s3.y) * (1.f / 1024.f);
    f[2] = (s0.z + s1.z + s2.z + s3.z) * (1.f / 1024.f);
    f[3] = (s0.w + s1.w + s2.w + s3.w) * (1.f / 1024.f);

    float a0r[4], a0i[4], a1r[4], a1i[4];
#pragma unroll
    for (int i = 0; i < 4; ++i) {
      float cy, sy, cx, sx;
      __sincosf(0.5f * f[i], &sy, &cy);
      __sincosf(0.5f * uload(qp + i), &sx, &cx);
      a0r[i] = cx * cy; a0i[i] = -sx * sy;
      a1r[i] = cx * sy; a1i[i] = -sx * cy;
    }

    float pr[16], pi[16];
#pragma unroll
    for (int j = 0; j < 16; ++j) {
      float rr = 1.f, ii = 0.f;
#pragma unroll
      for (int wi = 0; wi < 4; ++wi) {
        int bit = (j >> (3 - wi)) & 1;
        float ar = bit ? a1r[wi] : a0r[wi];
        float ai = bit ? a1i[wi] : a0i[wi];
        float t = rr * ar - ii * ai;
        ii = rr * ai + ii * ar;
        rr = t;
      }
      pr[j] = rr; pi[j] = ii;
    }

    // Composed CNOT(0,1);CNOT(1,2);CNOT(2,3): new[j] = old[comp[j]]
    constexpr int comp[16] = {0, 1, 3, 2, 6, 7, 5, 4, 12, 13, 15, 14, 10, 11, 9, 8};
#pragma unroll
    for (int i = 0; i < 4; ++i) qv2[half][i] = 0.f;
#pragma unroll
    for (int j = 0; j < 16; ++j) {
      int s = comp[j];
      float p = pr[s] * pr[s] + pi[s] * pi[s];
#pragma unroll
      for (int i = 0; i < 4; ++i)
        qv2[half][i] += ((j >> (3 - i)) & 1) ? -p : p;
    }
#pragma unroll
    for (int i = 0; i < 4; ++i) {
      v[i]     += qv2[half][i];
      v[4 + i] += qv2[half][i] * qv2[half][i];
    }
  }

#pragma unroll
  for (int k = 0; k < 8; ++k)
#pragma unroll
    for (int off = 32; off > 0; off >>= 1) v[k] += __shfl_down(v[k], off);
  if (lane == 0) {
#pragma unroll
    for (int k = 0; k < 8; ++k) tsum[w][k] = v[k];
  }
  __syncthreads();
  if (tid < 8) {
    float s = tsum[0][tid] + tsum[1][tid] + tsum[2][tid] + tsum[3][tid];
    tstats[tid] = s * (1.f / 512.f);
  }
  __syncthreads();

#pragma unroll 1
  for (int half = 0; half < 2; ++half) {
    const int bt = tid + half * 256;
    float nm[4];
#pragma unroll
    for (int i = 0; i < 4; ++i) {
      float mu  = tstats[i];
      float var = tstats[4 + i] - mu * mu;
      nm[i] = uload(gamma + i) * (qv2[half][i] - mu) * rsqrtf(var + EPS) +
              uload(beta + i);
    }
#pragma unroll
    for (int k = 0; k < 4; ++k) {
      float o = uload(hb + k);
#pragma unroll
      for (int i = 0; i < 4; ++i) o = fmaf(nm[i], uload(hw + k * 4 + i), o);
      out[bt * 4 + k] = o;
    }
  }
}

extern "C" void kernel_launch(void* const* d_in, const int* in_sizes, int n_in,
                              void* d_out, int out_size, void* d_ws, size_t ws_size,
                              hipStream_t stream) {
  const float* x  = (const float*)d_in[0];
  const float* w1 = (const float*)d_in[1];
  const float* b1 = (const float*)d_in[2];
  const float* w2 = (const float*)d_in[3];
  const float* b2 = (const float*)d_in[4];
  const float* qp = (const float*)d_in[5];
  const float* gm = (const float*)d_in[6];
  const float* bt = (const float*)d_in[7];
  const float* hw = (const float*)d_in[8];
  const float* hb = (const float*)d_in[9];
  float* out = (float*)d_out;

  float* partials = (float*)d_ws;  // 512 * 4 strips * 4 oc floats = 32 KB
  unsigned int* counter = (unsigned int*)((char*)d_ws + (32 << 10));

  // d_ws is re-poisoned to 0xAA before every timed launch -> zero the counter
  // on-stream (graph-capture-safe; the harness itself uses hipMemsetAsync).
  hipMemsetAsync(counter, 0, sizeof(unsigned int), stream);
  k12_fused<<<512 * 4, 256, 0, stream>>>(x, w1, b1, w2, b2, partials, counter,
                                         qp, gm, bt, hw, hb, out);
}

// Round 11
// 119.739 us; speedup vs baseline: 1.2457x; 1.2457x over previous
//
#include <hip/hip_runtime.h>

#define EPS 1e-5f

typedef float f2 __attribute__((ext_vector_type(2)));
typedef float f4 __attribute__((ext_vector_type(4)));

// Broadcast a block-uniform load into an SGPR (scalars).
__device__ __forceinline__ float uload(const float* __restrict__ p) {
  return __int_as_float(__builtin_amdgcn_readfirstlane(__float_as_int(*p)));
}

__device__ __forceinline__ f2 fma2(f2 a, f2 b, f2 c) {
  return __builtin_elementwise_fma(a, b, c);
}
__device__ __forceinline__ f2 splat2(float s) { f2 r; r.x = s; r.y = s; return r; }

// ---------------------------------------------------------------------------
// K12: fused conv1(1->8)+ReLU+pool + conv2(4 used oc of 16)+ReLU+pool + sum.
// Block = (batch b, quarter q): pooled2 rows 8q..8q+7, 256 threads.
// Hard-won notes (r1-r10):
//  - conv1 reads x from GLOBAL. LDS xtile stride-2 reads = 1.06M conflict
//    cycles (r4). Never again.
//  - launch_bounds (256,6) -> scratch spill, 95 MB HBM writes (r5); r9's
//    batched-load pipeline (72 live floats) -> 5.6 MB spill. Keep (256,4)
//    and keep live arrays small.
//  - pk_fma halved VALU-busy to ~22 us (r7, matched prediction).
//  - r10: last-block tail fusion -> per-block device __threadfence + hot
//    atomic = ~30 us serialization (VALUBusy 50->29%). Tail stays a separate
//    kernel. Harness d_ws fill (~44 us) + input restore (~11 us) are fixed.
//  - This round (only change vs r8): first conv1 task's 12 global loads are
//    issued BEFORE the staging __syncthreads (they touch no LDS), hiding
//    their latency behind staging+barrier. 24 floats live across the sync.
// ---------------------------------------------------------------------------
__global__ __launch_bounds__(256, 4) void k12_fused(
    const float* __restrict__ x, const float* __restrict__ w1,
    const float* __restrict__ b1, const float* __restrict__ w2,
    const float* __restrict__ b2, float* __restrict__ partials) {
  __shared__ float p1[8][18][66];  // pooled1 tile; col idx = col+1 (halo)
  __shared__ float w1t[80];        // [k][oc8] transposed (72) + b1[8] at 72..
  __shared__ float w2t[292];       // [ic8][k9][oc4] transposed + b2[4] at 288..
  __shared__ float wred[4][4];

  const int q   = blockIdx.x & 3;
  const int b   = blockIdx.x >> 2;
  const int tid = threadIdx.x;
  const float* xb = x + (size_t)b * (128 * 128);

  auto c1_load = [&](int pos, float xin[4][6]) {
    const int gl = pos >> 5, i = pos & 31;
    const int G  = 16 * q - 1 + gl;
    const bool vG = ((unsigned)G) < 64u;
    const int xr0 = 2 * G - 1;
#pragma unroll
    for (int r = 0; r < 4; ++r) {
      const int row  = xr0 + r;
      const bool rok = vG && ((unsigned)row < 128u);
      const int rowc = min(max(row, 0), 127);
      const float* rp = xb + rowc * 128;
      const float le = rp[(i == 0) ? 0 : (4 * i - 1)];
      const f4 mid   = *(const f4*)(rp + 4 * i);        // 16B-aligned
      const float ri = rp[(i == 31) ? 127 : (4 * i + 4)];
      xin[r][0] = (rok && i != 0)  ? le    : 0.f;
      xin[r][1] = rok              ? mid.x : 0.f;
      xin[r][2] = rok              ? mid.y : 0.f;
      xin[r][3] = rok              ? mid.z : 0.f;
      xin[r][4] = rok              ? mid.w : 0.f;
      xin[r][5] = (rok && i != 31) ? ri    : 0.f;
    }
  };
  auto c1_compute = [&](int pos, const float xin[4][6]) {
    const int gl = pos >> 5, i = pos & 31;
    const int G  = 16 * q - 1 + gl;
    const bool vG = ((unsigned)G) < 64u;
    // Two sequential oc-halves so only 18+2 weight f2s are live at a time.
#pragma unroll 1
    for (int g = 0; g < 2; ++g) {
      f2 wpx[9][2], bias1[2];
#pragma unroll
      for (int k = 0; k < 9; ++k) {
        wpx[k][0] = *(const f2*)&w1t[k * 8 + 4 * g];
        wpx[k][1] = *(const f2*)&w1t[k * 8 + 4 * g + 2];
      }
      bias1[0] = *(const f2*)&w1t[72 + 4 * g];
      bias1[1] = *(const f2*)&w1t[72 + 4 * g + 2];
#pragma unroll
      for (int p = 0; p < 2; ++p)
#pragma unroll
        for (int h = 0; h < 2; ++h) {  // pooled col 2i+h
          f2 best = splat2(0.f);       // ReLU floor
#pragma unroll
          for (int dy = 0; dy < 2; ++dy)
#pragma unroll
            for (int dx = 0; dx < 2; ++dx) {
              f2 a = bias1[p];
#pragma unroll
              for (int ky = 0; ky < 3; ++ky)
#pragma unroll
                for (int kx = 0; kx < 3; ++kx)
                  a = fma2(wpx[ky * 3 + kx][p],
                           splat2(xin[dy + ky][2 * h + dx + kx]), a);
              best.x = fmaxf(best.x, a.x);
              best.y = fmaxf(best.y, a.y);
            }
          const int oc0 = 4 * g + 2 * p;
          p1[oc0][gl][2 * i + 1 + h]     = vG ? best.x : 0.f;
          p1[oc0 + 1][gl][2 * i + 1 + h] = vG ? best.y : 0.f;
        }
    }
  };

  // ---- stage weights transposed (LDS writes only) ----
  if (tid < 72) {
    int oc = tid / 9, k = tid % 9;
    w1t[k * 8 + oc] = w1[tid];
  } else if (tid < 80) {
    w1t[tid] = b1[tid - 72];
  }
  {
    int t = tid;  // first 288 floats of w2 = oc 0..3
    {
      int oc = t / 72, rem = t % 72, ic = rem / 9, k = rem % 9;
      w2t[(ic * 9 + k) * 4 + oc] = w2[t];
    }
    t = tid + 256;
    if (t < 288) {
      int oc = t / 72, rem = t % 72, ic = rem / 9, k = rem % 9;
      w2t[(ic * 9 + k) * 4 + oc] = w2[t];
    }
  }
  if (tid >= 80 && tid < 84) w2t[288 + tid - 80] = b2[tid - 80];
  // zero p1's SAME-padding halo columns (8 channels x 18 rows)
  if (tid >= 96 && tid < 240) {
    int t = tid - 96;
    int ic = t / 18, r = t % 18;
    p1[ic][r][0]  = 0.f;
    p1[ic][r][65] = 0.f;
  }

  // ---- task-0 global loads in flight across the barrier (global-only) ----
  float xin0[4][6];
  c1_load(tid, xin0);
  __syncthreads();

  // ---- conv1 + ReLU + pool, ALL 8 channels ----
  c1_compute(tid, xin0);
#pragma unroll 1
  for (int pos = tid + 256; pos < 576; pos += 256) {
    float xin[4][6];
    c1_load(pos, xin);
    c1_compute(pos, xin);
  }
  __syncthreads();

  // ---- conv2 (oc 0..3 packed as 2 f2 pairs) + ReLU + pool + sum ----
  const int px2  = tid & 31;
  const int py2l = tid >> 5;  // 0..7

  f2 acc[2][2][2];  // [ocpair p][dy][dx]
#pragma unroll
  for (int p = 0; p < 2; ++p) {
    const f2 bias = *(const f2*)&w2t[288 + 2 * p];
    acc[p][0][0] = bias; acc[p][0][1] = bias;
    acc[p][1][0] = bias; acc[p][1][1] = bias;
  }

#pragma unroll 1
  for (int ic = 0; ic < 8; ++ic) {
    float xin[4][4];
#pragma unroll
    for (int r = 0; r < 4; ++r) {
      // even 8B-aligned float2 reads — near-0 conflicts (r3)
      const f2* rp = (const f2*)&p1[ic][2 * py2l + r][2 * px2];
      f2 v0 = rp[0], v1 = rp[1];
      xin[r][0] = v0.x; xin[r][1] = v0.y; xin[r][2] = v1.x; xin[r][3] = v1.y;
    }
#pragma unroll
    for (int ky = 0; ky < 3; ++ky)
#pragma unroll
      for (int kx = 0; kx < 3; ++kx) {
        const int k = ky * 3 + kx;
        const f2 w0  = *(const f2*)&w2t[(ic * 9 + k) * 4];
        const f2 w1p = *(const f2*)&w2t[(ic * 9 + k) * 4 + 2];
#pragma unroll
        for (int dy = 0; dy < 2; ++dy)
#pragma unroll
          for (int dx = 0; dx < 2; ++dx) {
            const f2 xs = splat2(xin[dy + ky][dx + kx]);
            acc[0][dy][dx] = fma2(w0, xs, acc[0][dy][dx]);
            acc[1][dy][dx] = fma2(w1p, xs, acc[1][dy][dx]);
          }
      }
  }

  // ---- ReLU + 2x2 pool + spatial partial-sum ----
  const int lane = tid & 63, w = tid >> 6;
#pragma unroll
  for (int p = 0; p < 2; ++p) {
    f2 m01;
    m01.x = fmaxf(fmaxf(fmaxf(acc[p][0][0].x, acc[p][0][1].x),
                        fmaxf(acc[p][1][0].x, acc[p][1][1].x)), 0.f);
    m01.y = fmaxf(fmaxf(fmaxf(acc[p][0][0].y, acc[p][0][1].y),
                        fmaxf(acc[p][1][0].y, acc[p][1][1].y)), 0.f);
#pragma unroll
    for (int off = 32; off > 0; off >>= 1) {
      m01.x += __shfl_down(m01.x, off);
      m01.y += __shfl_down(m01.y, off);
    }
    if (lane == 0) { wred[w][2 * p] = m01.x; wred[w][2 * p + 1] = m01.y; }
  }
  __syncthreads();
  if (tid < 4) {
    float s = wred[0][tid] + wred[1][tid] + wred[2][tid] + wred[3][tid];
    partials[((size_t)b * 4 + q) * 4 + tid] = s;
  }
}

// ---------------------------------------------------------------------------
// K3: feats -> quantum circuit -> batchnorm (over batch=512) -> head.
// Single block, 512 threads; thread = batch element. Shuffle reductions.
// ---------------------------------------------------------------------------
__global__ __launch_bounds__(512) void k3_tail(
    const float* __restrict__ partials, const float* __restrict__ qp,
    const float* __restrict__ gamma, const float* __restrict__ beta,
    const float* __restrict__ hw, const float* __restrict__ hb,
    float* __restrict__ out) {
  __shared__ float wsum[8][8];
  __shared__ float stats[8];
  const int tid = threadIdx.x;  // batch index

  const f4* pp = (const f4*)(partials + tid * 16);
  f4 s0 = pp[0], s1 = pp[1], s2 = pp[2], s3 = pp[3];
  float f[4];
  f[0] = (s0.x + s1.x + s2.x + s3.x) * (1.f / 1024.f);
  f[1] = (s0.y + s1.y + s2.y + s3.y) * (1.f / 1024.f);
  f[2] = (s0.z + s1.z + s2.z + s3.z) * (1.f / 1024.f);
  f[3] = (s0.w + s1.w + s2.w + s3.w) * (1.f / 1024.f);

  float a0r[4], a0i[4], a1r[4], a1i[4];
#pragma unroll
  for (int i = 0; i < 4; ++i) {
    float cy, sy, cx, sx;
    __sincosf(0.5f * f[i], &sy, &cy);
    __sincosf(0.5f * uload(qp + i), &sx, &cx);
    a0r[i] = cx * cy; a0i[i] = -sx * sy;
    a1r[i] = cx * sy; a1i[i] = -sx * cy;
  }

  float pr[16], pi[16];
#pragma unroll
  for (int j = 0; j < 16; ++j) {
    float rr = 1.f, ii = 0.f;
#pragma unroll
    for (int w = 0; w < 4; ++w) {
      int bit = (j >> (3 - w)) & 1;
      float ar = bit ? a1r[w] : a0r[w];
      float ai = bit ? a1i[w] : a0i[w];
      float t = rr * ar - ii * ai;
      ii = rr * ai + ii * ar;
      rr = t;
    }
    pr[j] = rr; pi[j] = ii;
  }

  constexpr int comp[16] = {0, 1, 3, 2, 6, 7, 5, 4, 12, 13, 15, 14, 10, 11, 9, 8};
  float qv[4] = {0.f, 0.f, 0.f, 0.f};
#pragma unroll
  for (int j = 0; j < 16; ++j) {
    int s = comp[j];
    float p = pr[s] * pr[s] + pi[s] * pi[s];
#pragma unroll
    for (int i = 0; i < 4; ++i)
      qv[i] += ((j >> (3 - i)) & 1) ? -p : p;
  }

  float v[8];
#pragma unroll
  for (int i = 0; i < 4; ++i) { v[i] = qv[i]; v[4 + i] = qv[i] * qv[i]; }
#pragma unroll
  for (int k = 0; k < 8; ++k)
#pragma unroll
    for (int off = 32; off > 0; off >>= 1) v[k] += __shfl_down(v[k], off);
  const int lane = tid & 63, w = tid >> 6;
  if (lane == 0) {
#pragma unroll
    for (int k = 0; k < 8; ++k) wsum[w][k] = v[k];
  }
  __syncthreads();
  if (tid < 8) {
    float s = 0.f;
#pragma unroll
    for (int ww = 0; ww < 8; ++ww) s += wsum[ww][tid];
    stats[tid] = s * (1.f / 512.f);
  }
  __syncthreads();

  float nm[4];
#pragma unroll
  for (int i = 0; i < 4; ++i) {
    float mu  = stats[i];
    float var = stats[4 + i] - mu * mu;
    nm[i] = uload(gamma + i) * (qv[i] - mu) * rsqrtf(var + EPS) + uload(beta + i);
  }
#pragma unroll
  for (int k = 0; k < 4; ++k) {
    float o = uload(hb + k);
#pragma unroll
    for (int i = 0; i < 4; ++i) o = fmaf(nm[i], uload(hw + k * 4 + i), o);
    out[tid * 4 + k] = o;
  }
}

extern "C" void kernel_launch(void* const* d_in, const int* in_sizes, int n_in,
                              void* d_out, int out_size, void* d_ws, size_t ws_size,
                              hipStream_t stream) {
  const float* x  = (const float*)d_in[0];
  const float* w1 = (const float*)d_in[1];
  const float* b1 = (const float*)d_in[2];
  const float* w2 = (const float*)d_in[3];
  const float* b2 = (const float*)d_in[4];
  const float* qp = (const float*)d_in[5];
  const float* gm = (const float*)d_in[6];
  const float* bt = (const float*)d_in[7];
  const float* hw = (const float*)d_in[8];
  const float* hb = (const float*)d_in[9];
  float* out = (float*)d_out;

  float* partials = (float*)d_ws;  // 512 * 4 strips * 4 oc floats = 32 KB

  k12_fused<<<512 * 4, 256, 0, stream>>>(x, w1, b1, w2, b2, partials);
  k3_tail<<<1, 512, 0, stream>>>(partials, qp, gm, bt, hw, hb, out);
}